// Round 12
// baseline (145.029 us; speedup 1.0000x reference)
//
#include <hip/hip_runtime.h>
#include <hip/hip_bf16.h>

// N=10000 nodes, F=256, H=256, E=320000 edges.
//
// *** R12 = MEASUREMENT ROUND ***
// Identical to R11 except gemm_mfma is launched TWICE (idempotent: writes
// the same uv both times; same work every call -> graph-capture safe).
// dur(R12) - dur(R11=116.8us) = gemm cost + 1 gap. Disambiguates whether
// the gemm is ~30us (budget model) or ~5us (cycle model) since it hides
// below the 44us harness fills in the top-5 profile view.
//
// W1 = [W1a | W1b]:  U' = x @ W1a^T + b1 (bias folded), V = x @ W1b^T
// out[e] = sigmoid(b2 + sum_j relu(U'[row][j] + V[col][j]) * W2[j])
// uv layout (fp8 e4m3, HW cvt): uv[node] = 512 bytes: [0:256]=U', [256:512]=V.
//
// Journal: R6 fused coop kernel -> reg spill (288us). R8/R9 sort-for-
// locality -> sort costs 75-96us >> ~20us locality gain. R7 deeper ILP ->
// neutral (edge line-throughput bound). R11 fp8 uv: -14.7us (line halving).
// Harness tax ~52us/window (268MB ws poison fill + restores).

typedef __attribute__((ext_vector_type(8))) short bf16x8;
typedef __attribute__((ext_vector_type(4))) float f32x4;
typedef __attribute__((ext_vector_type(2))) float f32x2;

__device__ __forceinline__ unsigned short f2bf(float f) {
    __hip_bfloat16 h = __float2bfloat16(f);
    return *reinterpret_cast<unsigned short*>(&h);
}

__device__ __forceinline__ unsigned char f2fp8(float f) {
    return (unsigned char)(__builtin_amdgcn_cvt_pk_fp8_f32(f, f, 0, false) & 0xff);
}

// ---------------------------------------------------------------------------
// Kernel 0: convert W1 (256x512 fp32) to bf16. Tiny (~2us).
// ---------------------------------------------------------------------------
__global__ __launch_bounds__(256) void convert_w(const float* __restrict__ w1,
                                                 unsigned short* __restrict__ wb,
                                                 int nw4) {
    int i = blockIdx.x * 256 + threadIdx.x;
    if (i < nw4) {
        float4 v = ((const float4*)w1)[i];
        ushort4 o = {f2bf(v.x), f2bf(v.y), f2bf(v.z), f2bf(v.w)};
        ((ushort4*)wb)[i] = o;
    }
}

// ---------------------------------------------------------------------------
// Kernel 1 (R11): block = 16 rows x 512 cols. Wave w owns cols w*128..+127.
// Per ktile: stage A (16x32 fp32->bf16) in dbuf LDS; 1 ds_read_b128 A-frag
// + 8x16B B-frags (L2-resident wb) + 8 MFMA 16x16x32. fp8 epilogue.
// ---------------------------------------------------------------------------
__global__ __launch_bounds__(256) void gemm_mfma(const float* __restrict__ x,
                                                 const unsigned short* __restrict__ wb,
                                                 const float* __restrict__ b1,
                                                 unsigned char* __restrict__ uv,
                                                 int M) {
    __shared__ __align__(16) unsigned short As[2][16][40];

    const int t    = threadIdx.x;
    const int wave = t >> 6;
    const int lane = t & 63;
    const int lm   = lane & 15;
    const int lq   = lane >> 4;
    const int lk   = lq * 8;
    const int m0   = blockIdx.x * 16;

    const int srow = t >> 4;
    const int sk   = (t & 15) * 2;
    const int grow = m0 + srow;
    const float* sptr = x + (size_t)(grow < M ? grow : (M - 1)) * 256 + sk;

    const int half    = wave >> 1;
    const int colbase = wave * 128;
    const int rowbase = (wave & 1) * 128;
    const unsigned short* bpre =
        wb + (size_t)(rowbase + lm) * 512 + half * 256 + lk;

    f32x4 acc[8];
#pragma unroll
    for (int j = 0; j < 8; ++j) acc[j] = f32x4{0.f, 0.f, 0.f, 0.f};

    float2 apref = *(const float2*)(sptr);

#pragma unroll
    for (int it = 0; it < 8; ++it) {
        const int kt  = it * 32;
        const int cur = it & 1;
        unsigned int lo = ((unsigned int)f2bf(apref.x));
        unsigned int hi = ((unsigned int)f2bf(apref.y)) << 16;
        *(unsigned int*)&As[cur][srow][sk] = lo | hi;
        if (it < 7) apref = *(const float2*)(sptr + kt + 32);
        __syncthreads();
        bf16x8 a = *(const bf16x8*)&As[cur][lm][lk];
#pragma unroll
        for (int j = 0; j < 8; ++j) {
            bf16x8 b = *(const bf16x8*)(bpre + (size_t)j * 16 * 512 + kt);
            acc[j] = __builtin_amdgcn_mfma_f32_16x16x32_bf16(a, b, acc[j], 0, 0, 0);
        }
    }

    const int row0 = m0 + lq * 4;
#pragma unroll
    for (int j = 0; j < 8; ++j) {
        const int col  = colbase + j * 16 + lm;
        const int cin  = col & 255;
        const float badd = half ? 0.f : b1[cin];
#pragma unroll
        for (int r = 0; r < 4; ++r) {
            if (row0 + r < M)
                uv[(size_t)(row0 + r) * 512 + col] = f2fp8(acc[j][r] + badd);
        }
    }
}

// ---------------------------------------------------------------------------
// Kernel 2 (R11): edge phase over fp8 uv. 4 edges/batch; per lane one uint4
// (16 fp8) per U row + one per V row; two batches per iteration; HW decode.
// ---------------------------------------------------------------------------
__global__ __launch_bounds__(256) void edge_kernel(const unsigned char* __restrict__ uv,
                                                   const int* __restrict__ ei,
                                                   const float* __restrict__ w2,
                                                   const float* __restrict__ b2p,
                                                   float* __restrict__ out, int E) {
    const int lane = threadIdx.x & 63;
    const int g = lane >> 4;
    const int c = lane & 15;
    const int wid  = (blockIdx.x * blockDim.x + threadIdx.x) >> 6;
    const int nwav = (gridDim.x * blockDim.x) >> 6;
    const int nb   = E >> 2;

    float w2r[16];
#pragma unroll
    for (int i = 0; i < 4; ++i)
        *(float4*)&w2r[i * 4] = *(const float4*)(w2 + c * 16 + i * 4);
    const float b2 = b2p[0];

    for (int b = wid; b < nb; b += 2 * nwav) {
        const int bB = b + nwav;
        const bool has2 = bB < nb;

        const int e0 = b * 4 + g;
        const int r0 = ei[e0];
        const int c0 = ei[E + e0];
        const int e1 = has2 ? bB * 4 + g : e0;
        const int r1 = ei[e1];
        const int c1 = ei[E + e1];

        uint4 ua = *(const uint4*)(uv + (size_t)r0 * 512 + c * 16);
        uint4 va = *(const uint4*)(uv + (size_t)c0 * 512 + 256 + c * 16);
        uint4 ub = *(const uint4*)(uv + (size_t)r1 * 512 + c * 16);
        uint4 vb = *(const uint4*)(uv + (size_t)c1 * 512 + 256 + c * 16);

        unsigned int uw[4], vw[4];
        float p;

        // ---- batch A ----
        *(uint4*)&uw[0] = ua; *(uint4*)&vw[0] = va;
        {
            float2 p2 = {0.f, 0.f};
#pragma unroll
            for (int w = 0; w < 4; ++w) {
                f32x2 u01 = __builtin_amdgcn_cvt_pk_f32_fp8(uw[w], false);
                f32x2 u23 = __builtin_amdgcn_cvt_pk_f32_fp8(uw[w], true);
                f32x2 v01 = __builtin_amdgcn_cvt_pk_f32_fp8(vw[w], false);
                f32x2 v23 = __builtin_amdgcn_cvt_pk_f32_fp8(vw[w], true);
                float s0 = fmaxf(u01.x + v01.x, 0.f);
                float s1 = fmaxf(u01.y + v01.y, 0.f);
                float s2 = fmaxf(u23.x + v23.x, 0.f);
                float s3 = fmaxf(u23.y + v23.y, 0.f);
                p2.x = fmaf(s0, w2r[4 * w + 0], p2.x);
                p2.y = fmaf(s1, w2r[4 * w + 1], p2.y);
                p2.x = fmaf(s2, w2r[4 * w + 2], p2.x);
                p2.y = fmaf(s3, w2r[4 * w + 3], p2.y);
            }
            p = p2.x + p2.y;
        }
#pragma unroll
        for (int off = 1; off < 16; off <<= 1)
            p += __shfl_xor(p, off, 64);
        if (c == 0) out[e0] = 1.f / (1.f + __expf(-(p + b2)));

        // ---- batch B ----
        if (has2) {
            *(uint4*)&uw[0] = ub; *(uint4*)&vw[0] = vb;
            float2 p2 = {0.f, 0.f};
#pragma unroll
            for (int w = 0; w < 4; ++w) {
                f32x2 u01 = __builtin_amdgcn_cvt_pk_f32_fp8(uw[w], false);
                f32x2 u23 = __builtin_amdgcn_cvt_pk_f32_fp8(uw[w], true);
                f32x2 v01 = __builtin_amdgcn_cvt_pk_f32_fp8(vw[w], false);
                f32x2 v23 = __builtin_amdgcn_cvt_pk_f32_fp8(vw[w], true);
                float s0 = fmaxf(u01.x + v01.x, 0.f);
                float s1 = fmaxf(u01.y + v01.y, 0.f);
                float s2 = fmaxf(u23.x + v23.x, 0.f);
                float s3 = fmaxf(u23.y + v23.y, 0.f);
                p2.x = fmaf(s0, w2r[4 * w + 0], p2.x);
                p2.y = fmaf(s1, w2r[4 * w + 1], p2.y);
                p2.x = fmaf(s2, w2r[4 * w + 2], p2.x);
                p2.y = fmaf(s3, w2r[4 * w + 3], p2.y);
            }
            p = p2.x + p2.y;
#pragma unroll
            for (int off = 1; off < 16; off <<= 1)
                p += __shfl_xor(p, off, 64);
            if (c == 0) out[e1] = 1.f / (1.f + __expf(-(p + b2)));
        }
    }
}

extern "C" void kernel_launch(void* const* d_in, const int* in_sizes, int n_in,
                              void* d_out, int out_size, void* d_ws, size_t ws_size,
                              hipStream_t stream) {
    const float* x  = (const float*)d_in[0];
    const int*   ei = (const int*)d_in[1];
    const float* W1 = (const float*)d_in[2];
    const float* b1 = (const float*)d_in[3];
    const float* W2 = (const float*)d_in[4];
    const float* b2 = (const float*)d_in[5];
    float* out = (float*)d_out;

    const int N = in_sizes[0] / 256;   // 10000
    const int E = in_sizes[1] / 2;     // 320000

    unsigned char*  uv = (unsigned char*)d_ws;            // N*512 fp8 (5.12 MB)
    unsigned short* wb = (unsigned short*)(uv + (size_t)N * 512); // 256KB bf16

    const int nw4 = (256 * 512) / 4;
    convert_w<<<(nw4 + 255) / 256, 256, 0, stream>>>(W1, wb, nw4);

    // MEASUREMENT: gemm launched twice (idempotent). dur - 116.8us = gemm cost.
    gemm_mfma<<<(N + 15) / 16, 256, 0, stream>>>(x, wb, b1, uv, N);
    gemm_mfma<<<(N + 15) / 16, 256, 0, stream>>>(x, wb, b1, uv, N);

    edge_kernel<<<2048, 256, 0, stream>>>(uv, ei, W2, b2, out, E);
}

// Round 13
// 113.750 us; speedup vs baseline: 1.2750x; 1.2750x over previous
//
#include <hip/hip_runtime.h>
#include <hip/hip_bf16.h>

// N=10000 nodes, F=256, H=256, E=320000 edges.
//
// W1 = [W1a | W1b]:  U' = x @ W1a^T + b1 (bias folded), V = x @ W1b^T
// out[e] = sigmoid(b2 + sum_j relu(U'[row][j] + V[col][j]) * W2[j])
// uv layout (fp8 e4m3, HW cvt): uv[node] = 512 bytes: [0:256]=U', [256:512]=V.
//
// R12 measured the R5-structure gemm at 28us (94 TF): per-ktile barrier +
// LDS round-trip + L2 B-load latency vs only 8 MFMAs/wave/ktile, at 2.4
// blocks/CU. R13 gemm v6: stage the WHOLE 16x256 A-tile once (single
// barrier), barrier-free K-loop, grid (625,2) = 1250 blocks (~4.9/CU).
//
// Journal: R6 fused coop kernel -> reg spill (288us). R8/R9 sort-for-
// locality -> 75-96us sort >> ~20us gain. R7 deeper edge ILP -> neutral
// (edge is L2 line-throughput bound, ~20-25us at fp8 width). R11 fp8 uv:
// -14.7us. Harness tax ~52us/window (268MB ws poison fill + restores).

typedef __attribute__((ext_vector_type(8))) short bf16x8;
typedef __attribute__((ext_vector_type(4))) float f32x4;
typedef __attribute__((ext_vector_type(2))) float f32x2;

__device__ __forceinline__ unsigned short f2bf(float f) {
    __hip_bfloat16 h = __float2bfloat16(f);
    return *reinterpret_cast<unsigned short*>(&h);
}

__device__ __forceinline__ unsigned char f2fp8(float f) {
    return (unsigned char)(__builtin_amdgcn_cvt_pk_fp8_f32(f, f, 0, false) & 0xff);
}

// ---------------------------------------------------------------------------
// Kernel 0: convert W1 (256x512 fp32) to bf16. Tiny (~2us).
// ---------------------------------------------------------------------------
__global__ __launch_bounds__(256) void convert_w(const float* __restrict__ w1,
                                                 unsigned short* __restrict__ wb,
                                                 int nw4) {
    int i = blockIdx.x * 256 + threadIdx.x;
    if (i < nw4) {
        float4 v = ((const float4*)w1)[i];
        ushort4 o = {f2bf(v.x), f2bf(v.y), f2bf(v.z), f2bf(v.w)};
        ((ushort4*)wb)[i] = o;
    }
}

// ---------------------------------------------------------------------------
// Kernel 1 v6: grid (625, 2). Block = 16 rows x 256 cols; blockIdx.y = h
// selects output half (h=0: U cols 0..255, W1 k-half 0, fold b1;
// h=1: V cols 256..511, W1 k-half 256). Wave w owns 64 cols (4 n-tiles).
//
// Stage FULL 16x256 A-tile (fp32->bf16) to LDS once; ONE __syncthreads;
// then 8 ktiles x 4 MFMAs with zero barriers (compiler pipelines ds_read
// + B loads freely across ktiles). LDS row stride 264 shorts = 132 dwords
// == 4 mod 32 -> 2-way bank alias on ds_read_b128 (free, m136).
// A-frag: As[lm][kt + lq*8 .. +7]. B-frag t of n-tile j: W1 row
// (w*64 + j*16 + lm), k = h*256 + kt + lq*8 (natural W1 layout).
// C/D: col=lane&15, row=(lane>>4)*4+reg. fp8 epilogue.
// ---------------------------------------------------------------------------
__global__ __launch_bounds__(256) void gemm_mfma(const float* __restrict__ x,
                                                 const unsigned short* __restrict__ wb,
                                                 const float* __restrict__ b1,
                                                 unsigned char* __restrict__ uv,
                                                 int M) {
    __shared__ __align__(16) unsigned short As[16][264];   // 8.25 KB

    const int t    = threadIdx.x;
    const int wave = t >> 6;
    const int lane = t & 63;
    const int lm   = lane & 15;
    const int lq   = lane >> 4;
    const int lk   = lq * 8;
    const int m0   = blockIdx.x * 16;
    const int h    = blockIdx.y;               // 0: U half, 1: V half

    // ---- stage A: thread t covers row (t>>4), cols (t&15)*4 + i*64 ----
    {
        const int srow = t >> 4;
        const int scol = (t & 15) * 4;
        const int gr   = m0 + srow;
        const float* xr = x + (size_t)(gr < M ? gr : (M - 1)) * 256;
#pragma unroll
        for (int i = 0; i < 4; ++i) {
            float4 v = *(const float4*)(xr + scol + i * 64);
            ushort4 o = {f2bf(v.x), f2bf(v.y), f2bf(v.z), f2bf(v.w)};
            *(ushort4*)&As[srow][scol + i * 64] = o;
        }
    }
    __syncthreads();

    // B pointer: W1 row (wave*64 + j*16 + lm), k-half h
    const unsigned short* bpre =
        wb + (size_t)(wave * 64 + lm) * 512 + h * 256 + lk;

    f32x4 acc[4];
#pragma unroll
    for (int j = 0; j < 4; ++j) acc[j] = f32x4{0.f, 0.f, 0.f, 0.f};

#pragma unroll 4
    for (int kt = 0; kt < 256; kt += 32) {
        bf16x8 a = *(const bf16x8*)&As[lm][kt + lk];
#pragma unroll
        for (int j = 0; j < 4; ++j) {
            bf16x8 b = *(const bf16x8*)(bpre + (size_t)j * 16 * 512 + kt);
            acc[j] = __builtin_amdgcn_mfma_f32_16x16x32_bf16(a, b, acc[j], 0, 0, 0);
        }
    }

    const int row0 = m0 + lq * 4;
#pragma unroll
    for (int j = 0; j < 4; ++j) {
        const int cin  = wave * 64 + j * 16 + lm;        // 0..255 within half
        const int col  = h * 256 + cin;                  // 0..511
        const float badd = h ? 0.f : b1[cin];
#pragma unroll
        for (int r = 0; r < 4; ++r) {
            if (row0 + r < M)
                uv[(size_t)(row0 + r) * 512 + col] = f2fp8(acc[j][r] + badd);
        }
    }
}

// ---------------------------------------------------------------------------
// Kernel 2 (R11): edge phase over fp8 uv. 4 edges/batch (g=lane>>4 slot,
// c=lane&15 col chunk); per lane one uint4 (16 fp8) per U row + one per V
// row; two independent batches per iteration; HW fp8 decode.
// ---------------------------------------------------------------------------
__global__ __launch_bounds__(256) void edge_kernel(const unsigned char* __restrict__ uv,
                                                   const int* __restrict__ ei,
                                                   const float* __restrict__ w2,
                                                   const float* __restrict__ b2p,
                                                   float* __restrict__ out, int E) {
    const int lane = threadIdx.x & 63;
    const int g = lane >> 4;
    const int c = lane & 15;
    const int wid  = (blockIdx.x * blockDim.x + threadIdx.x) >> 6;
    const int nwav = (gridDim.x * blockDim.x) >> 6;
    const int nb   = E >> 2;

    float w2r[16];
#pragma unroll
    for (int i = 0; i < 4; ++i)
        *(float4*)&w2r[i * 4] = *(const float4*)(w2 + c * 16 + i * 4);
    const float b2 = b2p[0];

    for (int b = wid; b < nb; b += 2 * nwav) {
        const int bB = b + nwav;
        const bool has2 = bB < nb;

        const int e0 = b * 4 + g;
        const int r0 = ei[e0];
        const int c0 = ei[E + e0];
        const int e1 = has2 ? bB * 4 + g : e0;
        const int r1 = ei[e1];
        const int c1 = ei[E + e1];

        uint4 ua = *(const uint4*)(uv + (size_t)r0 * 512 + c * 16);
        uint4 va = *(const uint4*)(uv + (size_t)c0 * 512 + 256 + c * 16);
        uint4 ub = *(const uint4*)(uv + (size_t)r1 * 512 + c * 16);
        uint4 vb = *(const uint4*)(uv + (size_t)c1 * 512 + 256 + c * 16);

        unsigned int uw[4], vw[4];
        float p;

        // ---- batch A ----
        *(uint4*)&uw[0] = ua; *(uint4*)&vw[0] = va;
        {
            float2 p2 = {0.f, 0.f};
#pragma unroll
            for (int w = 0; w < 4; ++w) {
                f32x2 u01 = __builtin_amdgcn_cvt_pk_f32_fp8(uw[w], false);
                f32x2 u23 = __builtin_amdgcn_cvt_pk_f32_fp8(uw[w], true);
                f32x2 v01 = __builtin_amdgcn_cvt_pk_f32_fp8(vw[w], false);
                f32x2 v23 = __builtin_amdgcn_cvt_pk_f32_fp8(vw[w], true);
                float s0 = fmaxf(u01.x + v01.x, 0.f);
                float s1 = fmaxf(u01.y + v01.y, 0.f);
                float s2 = fmaxf(u23.x + v23.x, 0.f);
                float s3 = fmaxf(u23.y + v23.y, 0.f);
                p2.x = fmaf(s0, w2r[4 * w + 0], p2.x);
                p2.y = fmaf(s1, w2r[4 * w + 1], p2.y);
                p2.x = fmaf(s2, w2r[4 * w + 2], p2.x);
                p2.y = fmaf(s3, w2r[4 * w + 3], p2.y);
            }
            p = p2.x + p2.y;
        }
#pragma unroll
        for (int off = 1; off < 16; off <<= 1)
            p += __shfl_xor(p, off, 64);
        if (c == 0) out[e0] = 1.f / (1.f + __expf(-(p + b2)));

        // ---- batch B ----
        if (has2) {
            *(uint4*)&uw[0] = ub; *(uint4*)&vw[0] = vb;
            float2 p2 = {0.f, 0.f};
#pragma unroll
            for (int w = 0; w < 4; ++w) {
                f32x2 u01 = __builtin_amdgcn_cvt_pk_f32_fp8(uw[w], false);
                f32x2 u23 = __builtin_amdgcn_cvt_pk_f32_fp8(uw[w], true);
                f32x2 v01 = __builtin_amdgcn_cvt_pk_f32_fp8(vw[w], false);
                f32x2 v23 = __builtin_amdgcn_cvt_pk_f32_fp8(vw[w], true);
                float s0 = fmaxf(u01.x + v01.x, 0.f);
                float s1 = fmaxf(u01.y + v01.y, 0.f);
                float s2 = fmaxf(u23.x + v23.x, 0.f);
                float s3 = fmaxf(u23.y + v23.y, 0.f);
                p2.x = fmaf(s0, w2r[4 * w + 0], p2.x);
                p2.y = fmaf(s1, w2r[4 * w + 1], p2.y);
                p2.x = fmaf(s2, w2r[4 * w + 2], p2.x);
                p2.y = fmaf(s3, w2r[4 * w + 3], p2.y);
            }
            p = p2.x + p2.y;
#pragma unroll
            for (int off = 1; off < 16; off <<= 1)
                p += __shfl_xor(p, off, 64);
            if (c == 0) out[e1] = 1.f / (1.f + __expf(-(p + b2)));
        }
    }
}

extern "C" void kernel_launch(void* const* d_in, const int* in_sizes, int n_in,
                              void* d_out, int out_size, void* d_ws, size_t ws_size,
                              hipStream_t stream) {
    const float* x  = (const float*)d_in[0];
    const int*   ei = (const int*)d_in[1];
    const float* W1 = (const float*)d_in[2];
    const float* b1 = (const float*)d_in[3];
    const float* W2 = (const float*)d_in[4];
    const float* b2 = (const float*)d_in[5];
    float* out = (float*)d_out;

    const int N = in_sizes[0] / 256;   // 10000
    const int E = in_sizes[1] / 2;     // 320000

    unsigned char*  uv = (unsigned char*)d_ws;            // N*512 fp8 (5.12 MB)
    unsigned short* wb = (unsigned short*)(uv + (size_t)N * 512); // 256KB bf16

    const int nw4 = (256 * 512) / 4;
    convert_w<<<(nw4 + 255) / 256, 256, 0, stream>>>(W1, wb, nw4);

    dim3 g((N + 15) / 16, 2);          // (625, 2) = 1250 blocks
    gemm_mfma<<<g, 256, 0, stream>>>(x, wb, b1, uv, N);

    edge_kernel<<<2048, 256, 0, stream>>>(uv, ei, W2, b2, out, E);
}